// Round 8
// baseline (435.195 us; speedup 1.0000x reference)
//
#include <hip/hip_runtime.h>
#include <hip/hip_bf16.h>

typedef __bf16 bf16x8 __attribute__((ext_vector_type(8)));
typedef __bf16 bf16x2 __attribute__((ext_vector_type(2)));
typedef float f32x4 __attribute__((ext_vector_type(4)));

#define K2f 2.0813689810056077f   // log2(e)^2
#define LN2f 0.6931471805599453f

// Kernel 1: prototypes f32 -> bf16 in MFMA B-fragment order + ysq2 = ||y||^2*log2e^2.
// Element e of class c, dim d (d = kk*32 + lg*8 + e) -> bf16 offset
// ((c>>4)*4 + kk)*64*8 + (lg*16 + (c&15))*8 + e.  Tile ct occupies 4096 B.
__global__ void dce_prep(const float* __restrict__ protos,
                         unsigned short* __restrict__ bpf,
                         float* __restrict__ ysq2) {
    int c = blockIdx.x;
    int lane = threadIdx.x;  // dims 2*lane, 2*lane+1
    float2 f = ((const float2*)(protos))[c * 64 + lane];
    int d0 = lane * 2;
    int kk = d0 >> 5, sub = d0 & 31, lg = sub >> 3, e = sub & 7;
    size_t o = (((size_t)((c >> 4) * 4 + kk) * 64) + lg * 16 + (c & 15)) * 8 + e;
    bf16x2 h;
    h.x = (__bf16)f.x;
    h.y = (__bf16)f.y;
    *(bf16x2*)(bpf + o) = h;
    float xs = f.x * f.x + f.y * f.y;
#pragma unroll
    for (int d = 1; d < 64; d <<= 1) xs += __shfl_xor(xs, d);
    if (lane == 0) ysq2[c] = xs * K2f;
}

// Kernel 2: fused distance-softmax-NLL. No barriers, no LDS staging; depth-1
// ping-pong register prefetch of frag-ordered B from L1/L2.
// 128-thread blocks (2 waves x 32 rows), grid = N/64 = 4096 (2x capacity);
// __launch_bounds__(128,8) forces 8-wave/SIMD register allocation.
// logits <= 0 -> softmax max pinned at 0:
//   nll = dist_label + ln2 * log2( sum_c 2^(-log2e * dist_c) ).
__global__ __launch_bounds__(128, 8) void dce_main(
    const float* __restrict__ feats,
    const float* __restrict__ protos,
    const unsigned short* __restrict__ bpf,
    const float* __restrict__ ysq2,
    const int* __restrict__ labels,
    float* __restrict__ partials, int C) {
    const int tid = threadIdx.x;   // 0..127
    const int lane = tid & 63;
    const int w = tid >> 6;        // 0..1
    const int row0 = blockIdx.x * 64;
    const int rbase = row0 + w * 32;
    const int lr = lane & 15;
    const int lg = lane >> 4;

    // ---- Phase 1: exact f32 label distance, 2 threads per row ----
    const int r1 = row0 + (tid >> 1);
    const int half = tid & 1;
    const int lab = labels[r1];
    const float4* fx = (const float4*)feats + (size_t)r1 * 32 + half * 16;
    const float4* px = (const float4*)protos + (size_t)lab * 32 + half * 16;
    float xx = 0.f, yy = 0.f, xy = 0.f;
#pragma unroll
    for (int i = 0; i < 16; ++i) {
        float4 f = fx[i], p = px[i];
        xx = fmaf(f.x, f.x, fmaf(f.y, f.y, fmaf(f.z, f.z, fmaf(f.w, f.w, xx))));
        yy = fmaf(p.x, p.x, fmaf(p.y, p.y, fmaf(p.z, p.z, fmaf(p.w, p.w, yy))));
        xy = fmaf(f.x, p.x, fmaf(f.y, p.y, fmaf(f.z, p.z, fmaf(f.w, p.w, xy))));
    }
    xx += __shfl_xor(xx, 1);
    yy += __shfl_xor(yy, 1);
    xy += __shfl_xor(xy, 1);
    const float ld = __builtin_amdgcn_sqrtf(fmaxf(fmaf(-2.f, xy, xx + yy), 0.f));

    // ---- A fragments: 2 M-frags x 4 k-slices ----
    bf16x8 a[2][4];
    const float4* f4 = (const float4*)feats;
#pragma unroll
    for (int m = 0; m < 2; ++m) {
        size_t r = (size_t)(rbase + m * 16 + lr);
#pragma unroll
        for (int kk = 0; kk < 4; ++kk) {
            size_t idx = r * 32 + kk * 8 + lg * 2;
            float4 lo = f4[idx];
            float4 hi = f4[idx + 1];
            bf16x8 v;
            v[0] = (__bf16)lo.x; v[1] = (__bf16)lo.y; v[2] = (__bf16)lo.z; v[3] = (__bf16)lo.w;
            v[4] = (__bf16)hi.x; v[5] = (__bf16)hi.y; v[6] = (__bf16)hi.z; v[7] = (__bf16)hi.w;
            a[m][kk] = v;
        }
    }

    // ||x||^2 (scaled) in C/D layout: element (m,reg) covers row m*16+lg*4+reg,
    // whose exact xx lives at wave-lane 2*(that row-in-wave).
    float xsqs[2][4];
#pragma unroll
    for (int m = 0; m < 2; ++m)
#pragma unroll
        for (int reg = 0; reg < 4; ++reg)
            xsqs[m][reg] = K2f * __shfl(xx, 2 * (m * 16 + lg * 4 + reg));

    float lacc[2][4];
#pragma unroll
    for (int m = 0; m < 2; ++m)
#pragma unroll
        for (int reg = 0; reg < 4; ++reg) lacc[m][reg] = 0.f;

    // Per-lane base pointers: per-tile address = base + t*4096 (+ kk*1024 imm).
    const char* bp = (const char*)bpf + (size_t)lane * 16;
    const float* ysp = ysq2 + lr;

#define LOADB(dst, yq, t)                                          \
    {                                                              \
        _Pragma("unroll") for (int kk = 0; kk < 4; ++kk)           \
            dst[kk] = *(const bf16x8*)(bp + (size_t)(t) * 4096 + kk * 1024); \
        yq = ysp[(t) * 16];                                        \
    }

#define COMPUTE(b, yq)                                                          \
    {                                                                           \
        _Pragma("unroll") for (int m = 0; m < 2; ++m) {                         \
            f32x4 acc = {0.f, 0.f, 0.f, 0.f};                                   \
            acc = __builtin_amdgcn_mfma_f32_16x16x32_bf16(a[m][0], b[0], acc, 0, 0, 0); \
            acc = __builtin_amdgcn_mfma_f32_16x16x32_bf16(a[m][1], b[1], acc, 0, 0, 0); \
            acc = __builtin_amdgcn_mfma_f32_16x16x32_bf16(a[m][2], b[2], acc, 0, 0, 0); \
            acc = __builtin_amdgcn_mfma_f32_16x16x32_bf16(a[m][3], b[3], acc, 0, 0, 0); \
            _Pragma("unroll") for (int reg = 0; reg < 4; ++reg) {               \
                float d = fmaf(-2.f * K2f, acc[reg], xsqs[m][reg] + yq);        \
                float s = __builtin_amdgcn_sqrtf(d);                            \
                lacc[m][reg] += __builtin_amdgcn_exp2f(-s);                     \
            }                                                                   \
        }                                                                       \
    }

    // ---- Main loop: depth-1 ping-pong register prefetch over 64 B tiles ----
    bf16x8 bA[4], bB[4];
    float yqA, yqB;
    LOADB(bA, yqA, 0);
    const int nt = C >> 4;  // 64 (even)
    for (int t = 0; t < nt - 2; t += 2) {
        LOADB(bB, yqB, t + 1);
        COMPUTE(bA, yqA);        // tile t   (overlaps bB loads)
        LOADB(bA, yqA, t + 2);
        COMPUTE(bB, yqB);        // tile t+1 (overlaps bA loads)
    }
    LOADB(bB, yqB, nt - 1);
    COMPUTE(bA, yqA);            // tile nt-2
    COMPUTE(bB, yqB);            // tile nt-1

#undef LOADB
#undef COMPUTE

    // ---- Reduce over 16 column-lanes per row, add exact label distance ----
    float ssum = 0.f;
#pragma unroll
    for (int m = 0; m < 2; ++m)
#pragma unroll
        for (int reg = 0; reg < 4; ++reg) {
            float l = lacc[m][reg];
            l += __shfl_xor(l, 1);
            l += __shfl_xor(l, 2);
            l += __shfl_xor(l, 4);
            l += __shfl_xor(l, 8);
            float ldv = __shfl(ld, 2 * (m * 16 + lg * 4 + reg));
            if (lr == 0) ssum += ldv + LN2f * __builtin_amdgcn_logf(l);
        }
    ssum += __shfl_xor(ssum, 16);
    ssum += __shfl_xor(ssum, 32);

    __shared__ float red[2];
    if (lane == 0) red[w] = ssum;
    __syncthreads();
    if (tid == 0) partials[blockIdx.x] = red[0] + red[1];
}

// Kernel 3: deterministic reduction of per-block partials -> mean.
__global__ void dce_finish(const float* __restrict__ partials,
                           float* __restrict__ out, int nblocks, float invN) {
    int tid = threadIdx.x;  // 256
    float s = 0.f;
    for (int i = tid; i < nblocks; i += 256) s += partials[i];
#pragma unroll
    for (int d = 1; d < 64; d <<= 1) s += __shfl_xor(s, d);
    __shared__ float red[4];
    if ((tid & 63) == 0) red[tid >> 6] = s;
    __syncthreads();
    if (tid == 0) out[0] = (red[0] + red[1] + red[2] + red[3]) * invN;
}

extern "C" void kernel_launch(void* const* d_in, const int* in_sizes, int n_in,
                              void* d_out, int out_size, void* d_ws, size_t ws_size,
                              hipStream_t stream) {
    const float* feats = (const float*)d_in[0];
    const float* protos = (const float*)d_in[1];
    const int* labels = (const int*)d_in[2];
    const int N = in_sizes[2];          // 262144
    const int C = in_sizes[1] / 128;    // 1024
    float* out = (float*)d_out;

    // Workspace: [bpf: C*128*2B][ysq2: C*4B][partials: N/64*4B]
    unsigned short* bpf = (unsigned short*)d_ws;
    float* ysq2 = (float*)((char*)d_ws + (size_t)C * 128 * 2);
    float* partials = ysq2 + C;
    const int nblocks = N / 64;   // 4096 blocks of 128 threads

    dce_prep<<<C, 64, 0, stream>>>(protos, bpf, ysq2);
    dce_main<<<nblocks, 128, 0, stream>>>(feats, protos, bpf, ysq2, labels, partials, C);
    dce_finish<<<1, 256, 0, stream>>>(partials, out, nblocks, 1.0f / (float)N);
}

// Round 9
// 141.504 us; speedup vs baseline: 3.0755x; 3.0755x over previous
//
#include <hip/hip_runtime.h>
#include <hip/hip_bf16.h>

typedef __bf16 bf16x8 __attribute__((ext_vector_type(8)));
typedef __bf16 bf16x2 __attribute__((ext_vector_type(2)));
typedef float f32x4 __attribute__((ext_vector_type(4)));

#define K2f 2.0813689810056077f   // log2(e)^2
#define LN2f 0.6931471805599453f

// Kernel 1: prototypes f32 -> bf16 in MFMA B-fragment order + ysq2 = ||y||^2*log2e^2.
// Element e of class c, dim d (d = kk*32 + lg*8 + e) -> bf16 offset
// ((c>>4)*4 + kk)*64*8 + (lg*16 + (c&15))*8 + e.  Tile ct occupies 4096 B.
__global__ void dce_prep(const float* __restrict__ protos,
                         unsigned short* __restrict__ bpf,
                         float* __restrict__ ysq2) {
    int c = blockIdx.x;
    int lane = threadIdx.x;  // dims 2*lane, 2*lane+1
    float2 f = ((const float2*)(protos))[c * 64 + lane];
    int d0 = lane * 2;
    int kk = d0 >> 5, sub = d0 & 31, lg = sub >> 3, e = sub & 7;
    size_t o = (((size_t)((c >> 4) * 4 + kk) * 64) + lg * 16 + (c & 15)) * 8 + e;
    bf16x2 h;
    h.x = (__bf16)f.x;
    h.y = (__bf16)f.y;
    *(bf16x2*)(bpf + o) = h;
    float xs = f.x * f.x + f.y * f.y;
#pragma unroll
    for (int d = 1; d < 64; d <<= 1) xs += __shfl_xor(xs, d);
    if (lane == 0) ysq2[c] = xs * K2f;
}

// Kernel 2: fused distance-softmax-NLL. No barriers, no LDS staging, no manual
// ping-pong: single B buffer streamed from L1/L2; TLP (target 5 waves/SIMD via
// launch_bounds(256,5)) hides the load latency. 2048 blocks x 256 threads;
// wave owns 32 rows (2 M-frags). logits <= 0 -> softmax max pinned at 0:
//   nll = dist_label + ln2 * log2( sum_c 2^(-log2e * dist_c) ).
__global__ __launch_bounds__(256, 5) void dce_main(
    const float* __restrict__ feats,
    const float* __restrict__ protos,
    const unsigned short* __restrict__ bpf,
    const float* __restrict__ ysq2,
    const int* __restrict__ labels,
    float* __restrict__ partials, int C) {
    const int tid = threadIdx.x;   // 0..255
    const int lane = tid & 63;
    const int w = tid >> 6;        // 0..3
    const int row0 = blockIdx.x * 128;
    const int rbase = row0 + w * 32;
    const int lr = lane & 15;
    const int lg = lane >> 4;

    // ---- Phase 1: exact f32 label distance, 2 threads per row ----
    const int r1 = row0 + (tid >> 1);
    const int half = tid & 1;
    const int lab = labels[r1];
    const float4* fx = (const float4*)feats + (size_t)r1 * 32 + half * 16;
    const float4* px = (const float4*)protos + (size_t)lab * 32 + half * 16;
    float xx = 0.f, yy = 0.f, xy = 0.f;
#pragma unroll
    for (int i = 0; i < 16; ++i) {
        float4 f = fx[i], p = px[i];
        xx = fmaf(f.x, f.x, fmaf(f.y, f.y, fmaf(f.z, f.z, fmaf(f.w, f.w, xx))));
        yy = fmaf(p.x, p.x, fmaf(p.y, p.y, fmaf(p.z, p.z, fmaf(p.w, p.w, yy))));
        xy = fmaf(f.x, p.x, fmaf(f.y, p.y, fmaf(f.z, p.z, fmaf(f.w, p.w, xy))));
    }
    xx += __shfl_xor(xx, 1);
    yy += __shfl_xor(yy, 1);
    xy += __shfl_xor(xy, 1);
    const float ld = __builtin_amdgcn_sqrtf(fmaxf(fmaf(-2.f, xy, xx + yy), 0.f));

    // ---- A fragments: 2 M-frags x 4 k-slices ----
    bf16x8 a[2][4];
    const float4* f4 = (const float4*)feats;
#pragma unroll
    for (int m = 0; m < 2; ++m) {
        size_t r = (size_t)(rbase + m * 16 + lr);
#pragma unroll
        for (int kk = 0; kk < 4; ++kk) {
            size_t idx = r * 32 + kk * 8 + lg * 2;
            float4 lo = f4[idx];
            float4 hi = f4[idx + 1];
            bf16x8 v;
            v[0] = (__bf16)lo.x; v[1] = (__bf16)lo.y; v[2] = (__bf16)lo.z; v[3] = (__bf16)lo.w;
            v[4] = (__bf16)hi.x; v[5] = (__bf16)hi.y; v[6] = (__bf16)hi.z; v[7] = (__bf16)hi.w;
            a[m][kk] = v;
        }
    }

    // ||x||^2 (scaled) in C/D layout: element (m,reg) covers row m*16+lg*4+reg,
    // whose exact xx lives at wave-lane 2*(that row-in-wave).
    float xsqs[2][4];
#pragma unroll
    for (int m = 0; m < 2; ++m)
#pragma unroll
        for (int reg = 0; reg < 4; ++reg)
            xsqs[m][reg] = K2f * __shfl(xx, 2 * (m * 16 + lg * 4 + reg));

    float lacc[2][4];
#pragma unroll
    for (int m = 0; m < 2; ++m)
#pragma unroll
        for (int reg = 0; reg < 4; ++reg) lacc[m][reg] = 0.f;

    // Per-lane base pointers: per-tile address = base + t*4096 (+ kk*1024 imm).
    const char* bp = (const char*)bpf + (size_t)lane * 16;
    const float* ysp = ysq2 + lr;

    // ---- Main loop over 64 B tiles: load -> 8 MFMA -> trans epilogue ----
    const int nt = C >> 4;  // 64
    for (int t = 0; t < nt; ++t) {
        bf16x8 b[4];
#pragma unroll
        for (int kk = 0; kk < 4; ++kk)
            b[kk] = *(const bf16x8*)(bp + (size_t)t * 4096 + kk * 1024);
        const float yq = ysp[t * 16];
#pragma unroll
        for (int m = 0; m < 2; ++m) {
            f32x4 acc = {0.f, 0.f, 0.f, 0.f};
            acc = __builtin_amdgcn_mfma_f32_16x16x32_bf16(a[m][0], b[0], acc, 0, 0, 0);
            acc = __builtin_amdgcn_mfma_f32_16x16x32_bf16(a[m][1], b[1], acc, 0, 0, 0);
            acc = __builtin_amdgcn_mfma_f32_16x16x32_bf16(a[m][2], b[2], acc, 0, 0, 0);
            acc = __builtin_amdgcn_mfma_f32_16x16x32_bf16(a[m][3], b[3], acc, 0, 0, 0);
#pragma unroll
            for (int reg = 0; reg < 4; ++reg) {
                float d = fmaf(-2.f * K2f, acc[reg], xsqs[m][reg] + yq);
                float s = __builtin_amdgcn_sqrtf(d);      // = log2e * dist
                lacc[m][reg] += __builtin_amdgcn_exp2f(-s);
            }
        }
    }

    // ---- Reduce over 16 column-lanes per row, add exact label distance ----
    float ssum = 0.f;
#pragma unroll
    for (int m = 0; m < 2; ++m)
#pragma unroll
        for (int reg = 0; reg < 4; ++reg) {
            float l = lacc[m][reg];
            l += __shfl_xor(l, 1);
            l += __shfl_xor(l, 2);
            l += __shfl_xor(l, 4);
            l += __shfl_xor(l, 8);
            float ldv = __shfl(ld, 2 * (m * 16 + lg * 4 + reg));
            if (lr == 0) ssum += ldv + LN2f * __builtin_amdgcn_logf(l);
        }
    ssum += __shfl_xor(ssum, 16);
    ssum += __shfl_xor(ssum, 32);

    __shared__ float red[4];
    if (lane == 0) red[w] = ssum;
    __syncthreads();
    if (tid == 0) partials[blockIdx.x] = red[0] + red[1] + red[2] + red[3];
}

// Kernel 3: deterministic reduction of per-block partials -> mean.
__global__ void dce_finish(const float* __restrict__ partials,
                           float* __restrict__ out, int nblocks, float invN) {
    int tid = threadIdx.x;  // 256
    float s = 0.f;
    for (int i = tid; i < nblocks; i += 256) s += partials[i];
#pragma unroll
    for (int d = 1; d < 64; d <<= 1) s += __shfl_xor(s, d);
    __shared__ float red[4];
    if ((tid & 63) == 0) red[tid >> 6] = s;
    __syncthreads();
    if (tid == 0) out[0] = (red[0] + red[1] + red[2] + red[3]) * invN;
}

extern "C" void kernel_launch(void* const* d_in, const int* in_sizes, int n_in,
                              void* d_out, int out_size, void* d_ws, size_t ws_size,
                              hipStream_t stream) {
    const float* feats = (const float*)d_in[0];
    const float* protos = (const float*)d_in[1];
    const int* labels = (const int*)d_in[2];
    const int N = in_sizes[2];          // 262144
    const int C = in_sizes[1] / 128;    // 1024
    float* out = (float*)d_out;

    // Workspace: [bpf: C*128*2B][ysq2: C*4B][partials: N/128*4B]
    unsigned short* bpf = (unsigned short*)d_ws;
    float* ysq2 = (float*)((char*)d_ws + (size_t)C * 128 * 2);
    float* partials = ysq2 + C;
    const int nblocks = N / 128;   // 2048 blocks of 256 threads

    dce_prep<<<C, 64, 0, stream>>>(protos, bpf, ysq2);
    dce_main<<<nblocks, 256, 0, stream>>>(feats, protos, bpf, ysq2, labels, partials, C);
    dce_finish<<<1, 256, 0, stream>>>(partials, out, nblocks, 1.0f / (float)N);
}

// Round 10
// 138.752 us; speedup vs baseline: 3.1365x; 1.0198x over previous
//
#include <hip/hip_runtime.h>
#include <hip/hip_bf16.h>

typedef __bf16 bf16x8 __attribute__((ext_vector_type(8)));
typedef __bf16 bf16x2 __attribute__((ext_vector_type(2)));
typedef float f32x4 __attribute__((ext_vector_type(4)));

#define LN2f 0.6931471805599453f
#define CEf  2.0402785445f   // log2(e) * sqrt(2): exp(-dist) = 2^(-CE*sqrt(sq_dist/2))

// Kernel 1: prototypes f32 -> bf16 in MFMA B-fragment order + ysqn = -0.5*||y||^2.
// Element e of class c, dim d (d = kk*32 + lg*8 + e) -> bf16 offset
// ((c>>4)*4 + kk)*64*8 + (lg*16 + (c&15))*8 + e.  Tile ct occupies 4096 B.
__global__ void dce_prep(const float* __restrict__ protos,
                         unsigned short* __restrict__ bpf,
                         float* __restrict__ ysqn) {
    int c = blockIdx.x;
    int lane = threadIdx.x;  // dims 2*lane, 2*lane+1
    float2 f = ((const float2*)(protos))[c * 64 + lane];
    int d0 = lane * 2;
    int kk = d0 >> 5, sub = d0 & 31, lg = sub >> 3, e = sub & 7;
    size_t o = (((size_t)((c >> 4) * 4 + kk) * 64) + lg * 16 + (c & 15)) * 8 + e;
    bf16x2 h;
    h.x = (__bf16)f.x;
    h.y = (__bf16)f.y;
    *(bf16x2*)(bpf + o) = h;
    float xs = f.x * f.x + f.y * f.y;
#pragma unroll
    for (int d = 1; d < 64; d <<= 1) xs += __shfl_xor(xs, d);
    if (lane == 0) ysqn[c] = -0.5f * xs;
}

// Kernel 2: fused distance-softmax-NLL. No barriers, no LDS staging; depth-1
// ping-pong register prefetch of frag-ordered B from L1/L2. 2048 blocks x 256
// threads; wave owns 32 rows (2 M-frags). Each wave starts its class-tile
// sweep at a staggered offset (wraps mod 64) so resident waves are phase-
// decorrelated (trans bursts interleave with other waves' loads/MFMA).
// Distance algebra folded into the MFMA accumulator:
//   acc_init = -(||x||^2+||y||^2)/2, acc_final = -sq_dist/2,
//   exp(-dist) = exp2(-CE * sqrt(-acc)).  logits <= 0 -> max pinned at 0:
//   nll = dist_label + ln2 * log2( sum_c exp2(-CE*sqrt(-acc_c)) ).
__global__ __launch_bounds__(256, 4) void dce_main(
    const float* __restrict__ feats,
    const float* __restrict__ protos,
    const unsigned short* __restrict__ bpf,
    const float* __restrict__ ysqn,
    const int* __restrict__ labels,
    float* __restrict__ partials, int C) {
    const int tid = threadIdx.x;   // 0..255
    const int lane = tid & 63;
    const int w = tid >> 6;        // 0..3
    const int row0 = blockIdx.x * 128;
    const int rbase = row0 + w * 32;
    const int lr = lane & 15;
    const int lg = lane >> 4;

    // ---- Phase 1: exact f32 label distance, 2 threads per row ----
    const int r1 = row0 + (tid >> 1);
    const int half = tid & 1;
    const int lab = labels[r1];
    const float4* fx = (const float4*)feats + (size_t)r1 * 32 + half * 16;
    const float4* px = (const float4*)protos + (size_t)lab * 32 + half * 16;
    float xx = 0.f, yy = 0.f, xy = 0.f;
#pragma unroll
    for (int i = 0; i < 16; ++i) {
        float4 f = fx[i], p = px[i];
        xx = fmaf(f.x, f.x, fmaf(f.y, f.y, fmaf(f.z, f.z, fmaf(f.w, f.w, xx))));
        yy = fmaf(p.x, p.x, fmaf(p.y, p.y, fmaf(p.z, p.z, fmaf(p.w, p.w, yy))));
        xy = fmaf(f.x, p.x, fmaf(f.y, p.y, fmaf(f.z, p.z, fmaf(f.w, p.w, xy))));
    }
    xx += __shfl_xor(xx, 1);
    yy += __shfl_xor(yy, 1);
    xy += __shfl_xor(xy, 1);
    const float ld = __builtin_amdgcn_sqrtf(fmaxf(fmaf(-2.f, xy, xx + yy), 0.f));

    // ---- A fragments: 2 M-frags x 4 k-slices ----
    bf16x8 a[2][4];
    const float4* f4 = (const float4*)feats;
#pragma unroll
    for (int m = 0; m < 2; ++m) {
        size_t r = (size_t)(rbase + m * 16 + lr);
#pragma unroll
        for (int kk = 0; kk < 4; ++kk) {
            size_t idx = r * 32 + kk * 8 + lg * 2;
            float4 lo = f4[idx];
            float4 hi = f4[idx + 1];
            bf16x8 v;
            v[0] = (__bf16)lo.x; v[1] = (__bf16)lo.y; v[2] = (__bf16)lo.z; v[3] = (__bf16)lo.w;
            v[4] = (__bf16)hi.x; v[5] = (__bf16)hi.y; v[6] = (__bf16)hi.z; v[7] = (__bf16)hi.w;
            a[m][kk] = v;
        }
    }

    // -0.5*||x||^2 arranged to the C/D layout: element (m,reg) covers row
    // m*16+lg*4+reg, whose exact xx lives at wave-lane 2*(that row-in-wave).
    float pre[2][4];
#pragma unroll
    for (int m = 0; m < 2; ++m)
#pragma unroll
        for (int reg = 0; reg < 4; ++reg)
            pre[m][reg] = -0.5f * __shfl(xx, 2 * (m * 16 + lg * 4 + reg));

    float lacc[2][4];
#pragma unroll
    for (int m = 0; m < 2; ++m)
#pragma unroll
        for (int reg = 0; reg < 4; ++reg) lacc[m][reg] = 0.f;

    // Per-lane base pointers: per-tile address = base + tt*4096 (+ kk*1024 imm).
    const char* bp = (const char*)bpf + (size_t)lane * 16;
    const float* ysp = ysqn + lr;

    // Phase stagger: wave-uniform starting tile, wraps mod 64.
    const int t0 = ((w << 4) + ((blockIdx.x & 15) << 2)) & 63;

#define LOADB(dst, yq, t)                                                     \
    {                                                                         \
        const int tt_ = (t0 + (t)) & 63;                                      \
        _Pragma("unroll") for (int kk = 0; kk < 4; ++kk)                      \
            dst[kk] = *(const bf16x8*)(bp + (size_t)tt_ * 4096 + kk * 1024);  \
        yq = ysp[tt_ * 16];                                                   \
    }

#define COMPUTE(b, yq)                                                          \
    {                                                                           \
        _Pragma("unroll") for (int m = 0; m < 2; ++m) {                         \
            f32x4 acc;                                                          \
            acc[0] = pre[m][0] + yq;                                            \
            acc[1] = pre[m][1] + yq;                                            \
            acc[2] = pre[m][2] + yq;                                            \
            acc[3] = pre[m][3] + yq;                                            \
            acc = __builtin_amdgcn_mfma_f32_16x16x32_bf16(a[m][0], b[0], acc, 0, 0, 0); \
            acc = __builtin_amdgcn_mfma_f32_16x16x32_bf16(a[m][1], b[1], acc, 0, 0, 0); \
            acc = __builtin_amdgcn_mfma_f32_16x16x32_bf16(a[m][2], b[2], acc, 0, 0, 0); \
            acc = __builtin_amdgcn_mfma_f32_16x16x32_bf16(a[m][3], b[3], acc, 0, 0, 0); \
            _Pragma("unroll") for (int reg = 0; reg < 4; ++reg) {               \
                float s = __builtin_amdgcn_sqrtf(-acc[reg]);  /* sqrt(sqd/2) */ \
                lacc[m][reg] += __builtin_amdgcn_exp2f(s * -CEf);               \
            }                                                                   \
        }                                                                       \
    }

    // ---- Main loop: depth-1 ping-pong register prefetch over 64 B tiles ----
    bf16x8 bA[4], bB[4];
    float yqA, yqB;
    LOADB(bA, yqA, 0);
    const int nt = C >> 4;  // 64 (even)
    for (int t = 0; t < nt - 2; t += 2) {
        LOADB(bB, yqB, t + 1);
        COMPUTE(bA, yqA);        // tile t   (overlaps bB loads)
        LOADB(bA, yqA, t + 2);
        COMPUTE(bB, yqB);        // tile t+1 (overlaps bA loads)
    }
    LOADB(bB, yqB, nt - 1);
    COMPUTE(bA, yqA);            // tile nt-2
    COMPUTE(bB, yqB);            // tile nt-1

#undef LOADB
#undef COMPUTE

    // ---- Reduce over 16 column-lanes per row, add exact label distance ----
    float ssum = 0.f;
#pragma unroll
    for (int m = 0; m < 2; ++m)
#pragma unroll
        for (int reg = 0; reg < 4; ++reg) {
            float l = lacc[m][reg];
            l += __shfl_xor(l, 1);
            l += __shfl_xor(l, 2);
            l += __shfl_xor(l, 4);
            l += __shfl_xor(l, 8);
            float ldv = __shfl(ld, 2 * (m * 16 + lg * 4 + reg));
            if (lr == 0) ssum += ldv + LN2f * __builtin_amdgcn_logf(l);
        }
    ssum += __shfl_xor(ssum, 16);
    ssum += __shfl_xor(ssum, 32);

    __shared__ float red[4];
    if (lane == 0) red[w] = ssum;
    __syncthreads();
    if (tid == 0) partials[blockIdx.x] = red[0] + red[1] + red[2] + red[3];
}

// Kernel 3: deterministic reduction of per-block partials -> mean.
__global__ void dce_finish(const float* __restrict__ partials,
                           float* __restrict__ out, int nblocks, float invN) {
    int tid = threadIdx.x;  // 256
    float s = 0.f;
    for (int i = tid; i < nblocks; i += 256) s += partials[i];
#pragma unroll
    for (int d = 1; d < 64; d <<= 1) s += __shfl_xor(s, d);
    __shared__ float red[4];
    if ((tid & 63) == 0) red[tid >> 6] = s;
    __syncthreads();
    if (tid == 0) out[0] = (red[0] + red[1] + red[2] + red[3]) * invN;
}

extern "C" void kernel_launch(void* const* d_in, const int* in_sizes, int n_in,
                              void* d_out, int out_size, void* d_ws, size_t ws_size,
                              hipStream_t stream) {
    const float* feats = (const float*)d_in[0];
    const float* protos = (const float*)d_in[1];
    const int* labels = (const int*)d_in[2];
    const int N = in_sizes[2];          // 262144
    const int C = in_sizes[1] / 128;    // 1024
    float* out = (float*)d_out;

    // Workspace: [bpf: C*128*2B][ysqn: C*4B][partials: N/128*4B]
    unsigned short* bpf = (unsigned short*)d_ws;
    float* ysqn = (float*)((char*)d_ws + (size_t)C * 128 * 2);
    float* partials = ysqn + C;
    const int nblocks = N / 128;   // 2048 blocks of 256 threads

    dce_prep<<<C, 64, 0, stream>>>(protos, bpf, ysqn);
    dce_main<<<nblocks, 256, 0, stream>>>(feats, protos, bpf, ysqn, labels, partials, C);
    dce_finish<<<1, 256, 0, stream>>>(partials, out, nblocks, 1.0f / (float)N);
}

// Round 11
// 127.172 us; speedup vs baseline: 3.4221x; 1.0911x over previous
//
#include <hip/hip_runtime.h>
#include <hip/hip_bf16.h>

typedef __bf16 bf16x8 __attribute__((ext_vector_type(8)));
typedef __bf16 bf16x2 __attribute__((ext_vector_type(2)));
typedef float f32x4 __attribute__((ext_vector_type(4)));

#define LN2f 0.6931471805599453f
#define CEf  2.0402785445f   // log2(e)*sqrt(2): exp(-dist) = 2^(-CE*sqrt(sq_dist/2))

typedef __attribute__((address_space(3))) unsigned int lds_u32;
typedef __attribute__((address_space(1))) unsigned int glb_u32;

__device__ __forceinline__ void gload16(const void* g, void* l) {
    __builtin_amdgcn_global_load_lds((const glb_u32*)g, (lds_u32*)l, 16, 0, 0);
}

// Kernel 1: prototypes f32 -> bf16 in MFMA B-fragment order + ysqn = -0.5*||y||^2.
// Element e of class c, dim d (d = kk*32 + lg*8 + e) -> bf16 offset
// ((c>>4)*4 + kk)*64*8 + (lg*16 + (c&15))*8 + e.  Tile ct occupies 4096 B.
__global__ void dce_prep(const float* __restrict__ protos,
                         unsigned short* __restrict__ bpf,
                         float* __restrict__ ysqn) {
    int c = blockIdx.x;
    int lane = threadIdx.x;  // dims 2*lane, 2*lane+1
    float2 f = ((const float2*)(protos))[c * 64 + lane];
    int d0 = lane * 2;
    int kk = d0 >> 5, sub = d0 & 31, lg = sub >> 3, e = sub & 7;
    size_t o = (((size_t)((c >> 4) * 4 + kk) * 64) + lg * 16 + (c & 15)) * 8 + e;
    bf16x2 h;
    h.x = (__bf16)f.x;
    h.y = (__bf16)f.y;
    *(bf16x2*)(bpf + o) = h;
    float xs = f.x * f.x + f.y * f.y;
#pragma unroll
    for (int d = 1; d < 64; d <<= 1) xs += __shfl_xor(xs, d);
    if (lane == 0) ysqn[c] = -0.5f * xs;
}

// Kernel 2: fused distance-softmax-NLL, chunked LDS staging.
// 2048 blocks x 256 threads; wave owns 32 rows (2 M-frags). B streamed in
// 16 KB chunks (4 class-tiles) via global_load_lds, double-buffered; ONE
// __syncthreads per chunk (16 total) -- stage for chunk n+1 issues at the top
// of chunk n's compute (~1400 cyc of cover), so the drain at the barrier is
// free. Cuts aggregate L2 B-traffic 4x (waves share the staged tile).
// Distance algebra folded into the accumulator:
//   acc_init = -(||x||^2+||y||^2)/2, acc_final = -sq_dist/2,
//   exp(-dist) = exp2(-CE*sqrt(-acc)).  logits <= 0 -> softmax max pinned at 0:
//   nll = dist_label + ln2 * log2( sum_c exp2(-CE*sqrt(-acc_c)) ).
__global__ __launch_bounds__(256, 4) void dce_main(
    const float* __restrict__ feats,
    const float* __restrict__ protos,
    const unsigned short* __restrict__ bpf,
    const float* __restrict__ ysqn,
    const int* __restrict__ labels,
    float* __restrict__ partials, int C) {
    const int tid = threadIdx.x;   // 0..255
    const int lane = tid & 63;
    const int w = tid >> 6;        // 0..3
    const int row0 = blockIdx.x * 128;
    const int rbase = row0 + w * 32;
    const int lr = lane & 15;
    const int lg = lane >> 4;

    __shared__ __align__(16) unsigned char bsm0[16384];
    __shared__ __align__(16) unsigned char bsm1[16384];
    __shared__ float red[4];

    const char* bpc = (const char*)bpf;
    // Chunk rotation: consecutive same-XCD blocks start on different chunks.
    const int c0 = (blockIdx.x >> 3) & 15;

#define STAGE(buf, chunkIdx)                                                   \
    {                                                                          \
        const char* src_ = bpc + (size_t)(chunkIdx) * 16384 + tid * 16;        \
        _Pragma("unroll") for (int kt = 0; kt < 4; ++kt)                       \
            gload16(src_ + kt * 4096, (buf) + kt * 4096 + tid * 16);           \
    }

    // ---- Issue first chunk's DMA immediately (lands under the prologue) ----
    STAGE(bsm0, c0);

    // ---- Phase 1: exact f32 label distance, 2 threads per row ----
    const int r1 = row0 + (tid >> 1);
    const int half = tid & 1;
    const int lab = labels[r1];
    const float4* fx = (const float4*)feats + (size_t)r1 * 32 + half * 16;
    const float4* px = (const float4*)protos + (size_t)lab * 32 + half * 16;
    float xx = 0.f, yy = 0.f, xy = 0.f;
#pragma unroll
    for (int i = 0; i < 16; ++i) {
        float4 f = fx[i], p = px[i];
        xx = fmaf(f.x, f.x, fmaf(f.y, f.y, fmaf(f.z, f.z, fmaf(f.w, f.w, xx))));
        yy = fmaf(p.x, p.x, fmaf(p.y, p.y, fmaf(p.z, p.z, fmaf(p.w, p.w, yy))));
        xy = fmaf(f.x, p.x, fmaf(f.y, p.y, fmaf(f.z, p.z, fmaf(f.w, p.w, xy))));
    }
    xx += __shfl_xor(xx, 1);
    yy += __shfl_xor(yy, 1);
    xy += __shfl_xor(xy, 1);
    const float ld = __builtin_amdgcn_sqrtf(fmaxf(fmaf(-2.f, xy, xx + yy), 0.f));

    // ---- A fragments: 2 M-frags x 4 k-slices ----
    bf16x8 a[2][4];
    const float4* f4 = (const float4*)feats;
#pragma unroll
    for (int m = 0; m < 2; ++m) {
        size_t r = (size_t)(rbase + m * 16 + lr);
#pragma unroll
        for (int kk = 0; kk < 4; ++kk) {
            size_t idx = r * 32 + kk * 8 + lg * 2;
            float4 lo = f4[idx];
            float4 hi = f4[idx + 1];
            bf16x8 v;
            v[0] = (__bf16)lo.x; v[1] = (__bf16)lo.y; v[2] = (__bf16)lo.z; v[3] = (__bf16)lo.w;
            v[4] = (__bf16)hi.x; v[5] = (__bf16)hi.y; v[6] = (__bf16)hi.z; v[7] = (__bf16)hi.w;
            a[m][kk] = v;
        }
    }

    // -0.5*||x||^2 in C/D layout: element (m,reg) covers row m*16+lg*4+reg,
    // whose exact xx lives at wave-lane 2*(that row-in-wave).
    float pre[2][4];
#pragma unroll
    for (int m = 0; m < 2; ++m)
#pragma unroll
        for (int reg = 0; reg < 4; ++reg)
            pre[m][reg] = -0.5f * __shfl(xx, 2 * (m * 16 + lg * 4 + reg));

    float lacc[2][4];
#pragma unroll
    for (int m = 0; m < 2; ++m)
#pragma unroll
        for (int reg = 0; reg < 4; ++reg) lacc[m][reg] = 0.f;

    const float* ysp = ysqn + lr;

#define TILE(buf, kt, tt)                                                       \
    {                                                                           \
        const bf16x8* bl_ = (const bf16x8*)((buf) + (kt) * 4096);               \
        bf16x8 b0 = bl_[lane];                                                  \
        bf16x8 b1 = bl_[64 + lane];                                             \
        bf16x8 b2 = bl_[128 + lane];                                            \
        bf16x8 b3 = bl_[192 + lane];                                            \
        const float yq_ = ysp[(tt) * 16];                                       \
        _Pragma("unroll") for (int m = 0; m < 2; ++m) {                         \
            f32x4 acc;                                                          \
            acc[0] = pre[m][0] + yq_;                                           \
            acc[1] = pre[m][1] + yq_;                                           \
            acc[2] = pre[m][2] + yq_;                                           \
            acc[3] = pre[m][3] + yq_;                                           \
            acc = __builtin_amdgcn_mfma_f32_16x16x32_bf16(a[m][0], b0, acc, 0, 0, 0); \
            acc = __builtin_amdgcn_mfma_f32_16x16x32_bf16(a[m][1], b1, acc, 0, 0, 0); \
            acc = __builtin_amdgcn_mfma_f32_16x16x32_bf16(a[m][2], b2, acc, 0, 0, 0); \
            acc = __builtin_amdgcn_mfma_f32_16x16x32_bf16(a[m][3], b3, acc, 0, 0, 0); \
            _Pragma("unroll") for (int reg = 0; reg < 4; ++reg) {               \
                float s_ = __builtin_amdgcn_sqrtf(-acc[reg]);                   \
                lacc[m][reg] += __builtin_amdgcn_exp2f(s_ * -CEf);              \
            }                                                                   \
        }                                                                       \
    }

    // ---- Chunk loop: 16 chunks x 4 tiles, double-buffered, 1 barrier/chunk --
    __syncthreads();  // chunk c0 resident in bsm0
#pragma unroll 2
    for (int ch = 0; ch < 16; ++ch) {
        unsigned char* curb = (ch & 1) ? bsm1 : bsm0;
        unsigned char* nxtb = (ch & 1) ? bsm0 : bsm1;
        const int ci = (c0 + ch) & 15;        // current chunk index
        if (ch + 1 < 16) {
            const int ni = (c0 + ch + 1) & 15;
            STAGE(nxtb, ni);
        }
#pragma unroll
        for (int kt = 0; kt < 4; ++kt) TILE(curb, kt, ci * 4 + kt);
        __syncthreads();  // drains stage DMA (landed long ago) + read fence
    }

#undef STAGE
#undef TILE

    // ---- Reduce over 16 column-lanes per row, add exact label distance ----
    float ssum = 0.f;
#pragma unroll
    for (int m = 0; m < 2; ++m)
#pragma unroll
        for (int reg = 0; reg < 4; ++reg) {
            float l = lacc[m][reg];
            l += __shfl_xor(l, 1);
            l += __shfl_xor(l, 2);
            l += __shfl_xor(l, 4);
            l += __shfl_xor(l, 8);
            float ldv = __shfl(ld, 2 * (m * 16 + lg * 4 + reg));
            if (lr == 0) ssum += ldv + LN2f * __builtin_amdgcn_logf(l);
        }
    ssum += __shfl_xor(ssum, 16);
    ssum += __shfl_xor(ssum, 32);

    if (lane == 0) red[w] = ssum;
    __syncthreads();
    if (tid == 0) partials[blockIdx.x] = red[0] + red[1] + red[2] + red[3];
}

// Kernel 3: deterministic reduction of per-block partials -> mean.
__global__ void dce_finish(const float* __restrict__ partials,
                           float* __restrict__ out, int nblocks, float invN) {
    int tid = threadIdx.x;  // 256
    float s = 0.f;
    for (int i = tid; i < nblocks; i += 256) s += partials[i];
#pragma unroll
    for (int d = 1; d < 64; d <<= 1) s += __shfl_xor(s, d);
    __shared__ float red[4];
    if ((tid & 63) == 0) red[tid >> 6] = s;
    __syncthreads();
    if (tid == 0) out[0] = (red[0] + red[1] + red[2] + red[3]) * invN;
}

extern "C" void kernel_launch(void* const* d_in, const int* in_sizes, int n_in,
                              void* d_out, int out_size, void* d_ws, size_t ws_size,
                              hipStream_t stream) {
    const float* feats = (const float*)d_in[0];
    const float* protos = (const float*)d_in[1];
    const int* labels = (const int*)d_in[2];
    const int N = in_sizes[2];          // 262144
    const int C = in_sizes[1] / 128;    // 1024
    float* out = (float*)d_out;

    // Workspace: [bpf: C*128*2B][ysqn: C*4B][partials: N/128*4B]
    unsigned short* bpf = (unsigned short*)d_ws;
    float* ysqn = (float*)((char*)d_ws + (size_t)C * 128 * 2);
    float* partials = ysqn + C;
    const int nblocks = N / 128;   // 2048 blocks of 256 threads

    dce_prep<<<C, 64, 0, stream>>>(protos, bpf, ysqn);
    dce_main<<<nblocks, 256, 0, stream>>>(feats, protos, bpf, ysqn, labels, partials, C);
    dce_finish<<<1, 256, 0, stream>>>(partials, out, nblocks, 1.0f / (float)N);
}